// Round 3
// baseline (1262.405 us; speedup 1.0000x reference)
//
#include <hip/hip_runtime.h>
#include <hip/hip_bf16.h>

typedef __bf16 bf16;
typedef __bf16 bf16x8 __attribute__((ext_vector_type(8)));
typedef float f32x4 __attribute__((ext_vector_type(4)));
typedef unsigned short u16;
typedef unsigned short u16x8 __attribute__((ext_vector_type(8)));

#define TT 16
#define BB 4
#define HH 64
#define WW 64
#define HID 64

__device__ __forceinline__ float sigm_f(float x) { return 1.f / (1.f + __expf(-x)); }
__device__ __forceinline__ float tanh_f(float x) { return 1.f - 2.f / (__expf(2.f * x) + 1.f); }

// x_seq fp32 [B,T,32,H,W] -> xb bf16 [T,B,H,W,32] (channel-last, t-major)
__global__ void xpose_kernel(const float* __restrict__ x, bf16* __restrict__ xb) {
  int idx = blockIdx.x * blockDim.x + threadIdx.x;
  const int total = TT * BB * HH * WW * 32;
  if (idx >= total) return;
  int c = idx & 31;
  int xx = (idx >> 5) & 63;
  int y = (idx >> 11) & 63;
  int b = (idx >> 17) & 3;
  int t = idx >> 19;
  float v = x[((((b * TT + t) * 32 + c) * HH + y) * WW + xx)];
  xb[idx] = (bf16)v;
}

// gw fp32 [256, CIN, 3, 3] -> bmat bf16 [K/32][256][32], k = tap*CIN + c,
// with gate-permuted output channel n': half=n'>>7, j=n'&127, gate=j>>5, hcl=j&31,
// orig o = gate*64 + half*32 + hcl.
template <int CIN>
__global__ void wprep_kernel(const float* __restrict__ gw, bf16* __restrict__ bmat,
                             const float* __restrict__ rw, bf16* __restrict__ rwb) {
  const int K = CIN * 9;
  int idx = blockIdx.x * blockDim.x + threadIdx.x;
  int total = 256 * K;
  if (idx < total) {
    int n = idx / K;
    int kk = idx - n * K;
    int half = n >> 7, j = n & 127, gate = j >> 5, hcl = j & 31;
    int o = gate * 64 + half * 32 + hcl;
    int tap = kk / CIN, c = kk - tap * CIN;
    int ky = tap / 3, kx = tap - ky * 3;
    float v = gw[((o * CIN + c) * 3 + ky) * 3 + kx];
    int kt = kk >> 5, kin = kk & 31;
    bmat[(kt * 256 + n) * 32 + kin] = (bf16)v;
  } else if (rw != nullptr) {
    int r = idx - total;
    if (r < 64 * 32) rwb[r] = (bf16)rw[r];
  }
}

// One fused ConvLSTM step for layer L at time t.
// xsrc: bf16 [T,B,H,W,Cx] channel-last. hbuf: bf16 [HS,B,H,W,64] (read slot t-1, write slot t).
// bmat: bf16 [KT][256][32]. cbuf: fp32 [B,H,W,64]. dout: fp32 [B,T,64,H,W] (L==2 only).
template <int L>
__global__ __launch_bounds__(512) void step_kernel(
    const bf16* __restrict__ xsrc, bf16* __restrict__ hbuf,
    const bf16* __restrict__ bmat, const float* __restrict__ gb,
    float* __restrict__ cbuf, const bf16* __restrict__ rwb,
    const float* __restrict__ rb, float* __restrict__ dout, int t) {
  constexpr int Cx = (L == 0) ? 32 : 64;
  constexpr int C = Cx + 64;
  constexpr int DIL = (L == 0) ? 1 : (L == 1 ? 2 : 4);
  constexpr int Wp = WW + 2 * DIL;
  constexpr int KT = (9 * C) / 32;       // 27 or 36
  constexpr int CT = C / 32;             // k-tiles per tap
  constexpr int HS = (L == 2) ? 2 : 16;  // h history slots

  __shared__ __align__(16) char smem[3 * Wp * C * 2 + 2 * 16384];
  char* alds = smem;                  // A tile (input), swizzled channel-last
  char* blds = smem + 3 * Wp * C * 2; // B double buffer

  int bid = blockIdx.x;
  int b = bid >> 6, y = bid & 63;
  int tid = threadIdx.x;

  // ---- B staging, T14-split: global->reg early, reg->LDS late ----
  struct Bregs { u16x8 lo, hi; };
  auto loadB = [&](int kt) {
    Bregs r;
    const bf16* src = bmat + (size_t)kt * 256 * 32;
    r.lo = *(const u16x8*)(src + (size_t)tid * 8);
    r.hi = *(const u16x8*)(src + (size_t)(tid + 512) * 8);
    return r;
  };
  auto writeB = [&](const Bregs& r, int kt) {
    char* dst = blds + (kt & 1) * 16384;
    {
      int j = tid;
      int n = j >> 2, kin8 = (j & 3) * 8;
      int off = (n * 32 + kin8) * 2;
      off ^= (n & 7) << 4;
      *(u16x8*)(dst + off) = r.lo;
    }
    {
      int j = tid + 512;
      int n = j >> 2, kin8 = (j & 3) * 8;
      int off = (n * 32 + kin8) * 2;
      off ^= (n & 7) << 4;
      *(u16x8*)(dst + off) = r.hi;
    }
  };

  Bregs breg = loadB(0);

  // ---- stage A tile: rows y-DIL, y, y+DIL; cols [-DIL, 64+DIL); zero-padded ----
  {
    const int chunks = 3 * Wp * (C / 8);
    for (int i = tid; i < chunks; i += 512) {
      int cg = i % (C / 8);
      int rem = i / (C / 8);
      int col = rem % Wp;
      int row3 = rem / Wp;
      int c = cg * 8;
      int xs = col - DIL;
      int ys = y + (row3 - 1) * DIL;
      u16x8 v = {0, 0, 0, 0, 0, 0, 0, 0};
      if ((unsigned)xs < 64u && (unsigned)ys < 64u) {
        if (c < Cx) {
          v = *(const u16x8*)(xsrc + (size_t)(((t * BB + b) * HH + ys) * WW + xs) * Cx + c);
        } else if (t > 0) {
          int slot = (t - 1) & (HS - 1);
          v = *(const u16x8*)(hbuf + (size_t)(((slot * BB + b) * HH + ys) * WW + xs) * 64 + (c - Cx));
        }
      }
      int off = ((row3 * Wp + col) * C + c) * 2;
      off ^= (col & 7) << 4;
      *(u16x8*)(alds + off) = v;
    }
  }

  writeB(breg, 0);
  if (KT > 1) breg = loadB(1);

  int lane = tid & 63;
  int wave = tid >> 6;
  int pxg = wave & 3, half = wave >> 2;
  int pxbase = pxg * 16;
  int l15 = lane & 15, kgrp = lane >> 4;

  f32x4 acc[8];
  #pragma unroll
  for (int i = 0; i < 8; ++i) acc[i] = f32x4{0.f, 0.f, 0.f, 0.f};

  for (int kt = 0; kt < KT; ++kt) {
    __syncthreads();
    if (kt + 1 < KT) {
      writeB(breg, kt + 1);
      if (kt + 2 < KT) breg = loadB(kt + 2);
    }
    int tap = kt / CT;
    int cb = (kt % CT) * 32;
    int ky = tap / 3, kx = tap - ky * 3;
    int col = pxbase + l15 + kx * DIL;
    int aoff = ((ky * Wp + col) * C + cb + kgrp * 8) * 2;
    aoff ^= (col & 7) << 4;
    bf16x8 af = *(const bf16x8*)(alds + aoff);
    const char* bbase = blds + (kt & 1) * 16384;
    #pragma unroll
    for (int nt = 0; nt < 8; ++nt) {
      int n = half * 128 + nt * 16 + l15;
      int boff = (n * 32 + kgrp * 8) * 2;
      boff ^= (n & 7) << 4;
      bf16x8 bfr = *(const bf16x8*)(bbase + boff);
      acc[nt] = __builtin_amdgcn_mfma_f32_16x16x32_bf16(af, bfr, acc[nt], 0, 0, 0);
    }
  }

  // ---- epilogue: LSTM cell + residual + writes ----
  // lane owns pixels px = pxbase + kgrp*4 + r (r=0..3), hidden hc = half*32 + hcu*16 + l15.
  // acc[nt]: gate = nt>>1, hcu = nt&1  (via the n' permutation in wprep).
  #pragma unroll
  for (int hcu = 0; hcu < 2; ++hcu) {
    int hc = half * 32 + hcu * 16 + l15;
    float bi = gb[hc], bfg = gb[64 + hc], bgg = gb[128 + hc], bog = gb[192 + hc];
    f32x4 vi = acc[0 + hcu], vf = acc[2 + hcu], vg = acc[4 + hcu], vo = acc[6 + hcu];

    float rwv[32];
    float rbv = 0.f;
    if constexpr (L == 0) {
      rbv = rb[hc];
      const u16x8* rp = (const u16x8*)(rwb + hc * 32);
      #pragma unroll
      for (int q = 0; q < 4; ++q) {
        bf16x8 wb = *(const bf16x8*)(rp + q);
        #pragma unroll
        for (int e = 0; e < 8; ++e) rwv[q * 8 + e] = (float)wb[e];
      }
    }

    #pragma unroll
    for (int r = 0; r < 4; ++r) {
      int px = pxbase + kgrp * 4 + r;
      float giv = sigm_f(vi[r] + bi);
      float gfv = sigm_f(vf[r] + bfg);
      float ggv = tanh_f(vg[r] + bgg);
      float gov = sigm_f(vo[r] + bog);
      int cidx = ((b * HH + y) * WW + px) * 64 + hc;
      float cold = (t > 0) ? cbuf[cidx] : 0.f;
      float cn = gfv * cold + giv * ggv;
      cbuf[cidx] = cn;
      float hn = gov * tanh_f(cn);

      float res;
      int colc = px + DIL;  // center tap column in the staged tile
      if constexpr (L == 0) {
        float s = rbv;
        #pragma unroll
        for (int q = 0; q < 4; ++q) {
          int off = (((1 * Wp + colc) * C + q * 8) * 2) ^ ((colc & 7) << 4);
          bf16x8 xv = *(const bf16x8*)(alds + off);
          #pragma unroll
          for (int e = 0; e < 8; ++e) s += rwv[q * 8 + e] * (float)xv[e];
        }
        res = s;
      } else {
        int off = (((1 * Wp + colc) * C + hc) * 2) ^ ((colc & 7) << 4);
        res = (float)*(const bf16*)(alds + off);
      }
      float ho = hn + res;
      int hslot = t & (HS - 1);
      hbuf[(size_t)(((hslot * BB + b) * HH + y) * WW + px) * 64 + hc] = (bf16)ho;
      if constexpr (L == 2) {
        dout[(size_t)(((b * TT + t) * HID + hc) * HH + y) * WW + px] = ho;
      }
    }
  }
}

extern "C" void kernel_launch(void* const* d_in, const int* in_sizes, int n_in,
                              void* d_out, int out_size, void* d_ws, size_t ws_size,
                              hipStream_t stream) {
  const float* x_seq = (const float*)d_in[0];
  const float* gw0 = (const float*)d_in[1];
  const float* gb0 = (const float*)d_in[2];
  const float* gw1 = (const float*)d_in[3];
  const float* gb1 = (const float*)d_in[4];
  const float* gw2 = (const float*)d_in[5];
  const float* gb2 = (const float*)d_in[6];
  const float* rw0 = (const float*)d_in[7];
  const float* rb0 = (const float*)d_in[8];
  float* dout = (float*)d_out;

  char* ws = (char*)d_ws;
  size_t off = 0;
  auto carve = [&](size_t bytes) {
    char* p = ws + off;
    off += (bytes + 255) & ~(size_t)255;
    return p;
  };
  bf16* xb0 = (bf16*)carve((size_t)TT * BB * HH * WW * 32 * 2);   // 16.8 MB
  bf16* seqA = (bf16*)carve((size_t)TT * BB * HH * WW * 64 * 2);  // 33.6 MB
  bf16* seqB = (bf16*)carve((size_t)TT * BB * HH * WW * 64 * 2);  // 33.6 MB
  bf16* hC = (bf16*)carve((size_t)2 * BB * HH * WW * 64 * 2);     // 4.2 MB
  float* cbuf = (float*)carve((size_t)BB * HH * WW * 64 * 4);     // 4.2 MB
  bf16* bm0 = (bf16*)carve((size_t)27 * 256 * 32 * 2);
  bf16* bm1 = (bf16*)carve((size_t)36 * 256 * 32 * 2);
  bf16* bm2 = (bf16*)carve((size_t)36 * 256 * 32 * 2);
  bf16* rwb = (bf16*)carve((size_t)64 * 32 * 2);

  {
    int total = TT * BB * HH * WW * 32;
    xpose_kernel<<<(total + 255) / 256, 256, 0, stream>>>(x_seq, xb0);
  }
  {
    int total = 256 * 96 * 9 + 64 * 32;
    wprep_kernel<96><<<(total + 255) / 256, 256, 0, stream>>>(gw0, bm0, rw0, rwb);
  }
  {
    int total = 256 * 128 * 9;
    wprep_kernel<128><<<(total + 255) / 256, 256, 0, stream>>>(gw1, bm1, nullptr, nullptr);
    wprep_kernel<128><<<(total + 255) / 256, 256, 0, stream>>>(gw2, bm2, nullptr, nullptr);
  }

  for (int t = 0; t < TT; ++t)
    step_kernel<0><<<BB * HH, 512, 0, stream>>>(xb0, seqA, bm0, gb0, cbuf, rwb, rb0, nullptr, t);
  for (int t = 0; t < TT; ++t)
    step_kernel<1><<<BB * HH, 512, 0, stream>>>(seqA, seqB, bm1, gb1, cbuf, nullptr, nullptr, nullptr, t);
  for (int t = 0; t < TT; ++t)
    step_kernel<2><<<BB * HH, 512, 0, stream>>>(seqB, hC, bm2, gb2, cbuf, nullptr, nullptr, dout, t);
}

// Round 4
// 1245.983 us; speedup vs baseline: 1.0132x; 1.0132x over previous
//
#include <hip/hip_runtime.h>
#include <hip/hip_bf16.h>

typedef __bf16 bf16;
typedef __bf16 bf16x8 __attribute__((ext_vector_type(8)));
typedef float f32x4 __attribute__((ext_vector_type(4)));
typedef unsigned short u16;
typedef unsigned short u16x8 __attribute__((ext_vector_type(8)));

#define TT 16
#define BB 4
#define HH 64
#define WW 64
#define HID 64

__device__ __forceinline__ float sigm_f(float x) { return 1.f / (1.f + __expf(-x)); }
__device__ __forceinline__ float tanh_f(float x) { return 1.f - 2.f / (__expf(2.f * x) + 1.f); }

// x_seq fp32 [B,T,32,H,W] -> xb bf16 [T,B,H,W,32] (channel-last, t-major)
__global__ void xpose_kernel(const float* __restrict__ x, bf16* __restrict__ xb) {
  int idx = blockIdx.x * blockDim.x + threadIdx.x;
  const int total = TT * BB * HH * WW * 32;
  if (idx >= total) return;
  int c = idx & 31;
  int xx = (idx >> 5) & 63;
  int y = (idx >> 11) & 63;
  int b = (idx >> 17) & 3;
  int t = idx >> 19;
  float v = x[((((b * TT + t) * 32 + c) * HH + y) * WW + xx)];
  xb[idx] = (bf16)v;
}

// gw fp32 [256, CIN, 3, 3] -> bmat bf16 [K/32][256][32], k = tap*CIN + c.
// Gate permutation for 2m x 4n wave tiles: column n' -> orig channel o:
//   q = n'>>6 (ch-quarter), j = n'&63, g = j>>4 (gate), hcl = j&15,
//   o = g*64 + q*16 + hcl   (hidden ch hc = q*16 + hcl).
template <int CIN>
__global__ void wprep_kernel(const float* __restrict__ gw, bf16* __restrict__ bmat,
                             const float* __restrict__ rw, bf16* __restrict__ rwb) {
  const int K = CIN * 9;
  int idx = blockIdx.x * blockDim.x + threadIdx.x;
  int total = 256 * K;
  if (idx < total) {
    int n = idx / K;
    int kk = idx - n * K;
    int q = n >> 6, j = n & 63, g = j >> 4, hcl = j & 15;
    int o = g * 64 + q * 16 + hcl;
    int tap = kk / CIN, c = kk - tap * CIN;
    int ky = tap / 3, kx = tap - ky * 3;
    float v = gw[((o * CIN + c) * 3 + ky) * 3 + kx];
    int kt = kk >> 5, kin = kk & 31;
    bmat[(kt * 256 + n) * 32 + kin] = (bf16)v;
  } else if (rw != nullptr) {
    int r = idx - total;
    if (r < 64 * 32) rwb[r] = (bf16)rw[r];
  }
}

// One fused ConvLSTM step for layer L at time t.
// xsrc: bf16 [T,B,H,W,Cx] channel-last. hbuf: bf16 [HS,B,H,W,64].
// bmat: bf16 [KT][256][32]. cbuf: fp32 [B,H,W,64]. dout: fp32 [B,T,64,H,W] (L==2).
// A in LDS as [c-chunk j][row3][Wp][32ch] (64B rows, XOR-swizzled by col&7);
// B read directly from L1/L2 into registers, pipelined 2 k-tiles deep; no k-loop barriers.
template <int L>
__global__ __launch_bounds__(512, 2) void step_kernel(
    const bf16* __restrict__ xsrc, bf16* __restrict__ hbuf,
    const bf16* __restrict__ bmat, const float* __restrict__ gb,
    float* __restrict__ cbuf, const bf16* __restrict__ rwb,
    const float* __restrict__ rb, float* __restrict__ dout, int t) {
  constexpr int Cx = (L == 0) ? 32 : 64;
  constexpr int C = Cx + 64;
  constexpr int DIL = (L == 0) ? 1 : (L == 1 ? 2 : 4);
  constexpr int Wp = WW + 2 * DIL;
  constexpr int KT = (9 * C) / 32;       // 27 or 36
  constexpr int CT = C / 32;             // c-chunks (k-tiles per tap)
  constexpr int HS = (L == 2) ? 2 : 16;  // h history slots

  __shared__ __align__(16) char alds[CT * 3 * Wp * 64];

  int bid = blockIdx.x;
  int b = bid >> 6, y = bid & 63;
  int tid = threadIdx.x;
  int lane = tid & 63, wave = tid >> 6;
  int l15 = lane & 15, kgrp = lane >> 4;
  int pxg = wave >> 2, q = wave & 3;  // wave = pxg*4 + q

  const char* bmat_c = (const char*)bmat;
  const int voffB = q * 4096 + l15 * 64 + kgrp * 16;  // bytes into a 16KB k-tile

  bf16x8 bfr[4][4];
  auto loadB = [&](int slot, int kt) {
    #pragma unroll
    for (int g = 0; g < 4; ++g)
      bfr[slot][g] = *(const bf16x8*)(bmat_c + (size_t)kt * 16384 + voffB + g * 1024);
  };
  loadB(0, 0);
  loadB(1, 1);

  // ---- stage A tile: rows y-DIL, y, y+DIL; cols [-DIL, 64+DIL); zero-padded ----
  {
    const int chunks = 3 * Wp * (C / 8);
    for (int i = tid; i < chunks; i += 512) {
      int col = i % Wp;
      int rem = i / Wp;
      int row3 = rem % 3;
      int cg = rem / 3;
      int c = cg * 8;
      int j = cg >> 2, sub = cg & 3;
      int xs = col - DIL;
      int ys = y + (row3 - 1) * DIL;
      u16x8 v = {0, 0, 0, 0, 0, 0, 0, 0};
      if ((unsigned)xs < 64u && (unsigned)ys < 64u) {
        if (c < Cx) {
          v = *(const u16x8*)(xsrc + (size_t)(((t * BB + b) * HH + ys) * WW + xs) * Cx + c);
        } else if (t > 0) {
          int slot = (t - 1) & (HS - 1);
          v = *(const u16x8*)(hbuf + (size_t)(((slot * BB + b) * HH + ys) * WW + xs) * 64 + (c - Cx));
        }
      }
      int off = ((j * 3 + row3) * Wp + col) * 64 + sub * 16;
      off ^= (col & 7) << 4;
      *(u16x8*)(alds + off) = v;
    }
  }
  __syncthreads();

  // per-(m,kx) swizzled A base offsets (constant after unroll)
  int abase[2][3];
  #pragma unroll
  for (int m = 0; m < 2; ++m)
    #pragma unroll
    for (int kx = 0; kx < 3; ++kx) {
      int col = pxg * 32 + m * 16 + l15 + kx * DIL;
      abase[m][kx] = (col * 64 + kgrp * 16) ^ ((col & 7) << 4);
    }

  f32x4 acc[2][4];
  #pragma unroll
  for (int m = 0; m < 2; ++m)
    #pragma unroll
    for (int g = 0; g < 4; ++g) acc[m][g] = f32x4{0.f, 0.f, 0.f, 0.f};

  #pragma unroll
  for (int kt = 0; kt < KT; ++kt) {
    if (kt + 2 < KT) loadB((kt + 2) & 3, kt + 2);
    int tap = kt / CT;
    int j = kt - tap * CT;
    int ky = tap / 3, kx = tap - ky * 3;
    int imm = ((j * 3 + ky) * Wp) * 64;  // multiple of 256 — no overlap with swizzle bits
    bf16x8 a0 = *(const bf16x8*)(alds + abase[0][kx] + imm);
    bf16x8 a1 = *(const bf16x8*)(alds + abase[1][kx] + imm);
    #pragma unroll
    for (int g = 0; g < 4; ++g) {
      acc[0][g] = __builtin_amdgcn_mfma_f32_16x16x32_bf16(a0, bfr[kt & 3][g], acc[0][g], 0, 0, 0);
      acc[1][g] = __builtin_amdgcn_mfma_f32_16x16x32_bf16(a1, bfr[kt & 3][g], acc[1][g], 0, 0, 0);
    }
  }

  // ---- epilogue: LSTM cell + residual + writes ----
  // lane owns hidden ch hc = q*16 + l15; pixels px = pxg*32 + m*16 + kgrp*4 + r.
  // acc[m][g]: g = gate (i,f,g,o).
  int hc = q * 16 + l15;
  float bi = gb[hc], bfg = gb[64 + hc], bgg = gb[128 + hc], bog = gb[192 + hc];

  float rwv[32];
  float rbv = 0.f;
  if constexpr (L == 0) {
    rbv = rb[hc];
    const u16x8* rp = (const u16x8*)(rwb + hc * 32);
    #pragma unroll
    for (int p = 0; p < 4; ++p) {
      bf16x8 wb = *(const bf16x8*)(rp + p);
      #pragma unroll
      for (int e = 0; e < 8; ++e) rwv[p * 8 + e] = (float)wb[e];
    }
  }

  #pragma unroll
  for (int m = 0; m < 2; ++m) {
    f32x4 vi = acc[m][0], vf = acc[m][1], vg = acc[m][2], vo = acc[m][3];
    f32x4 hov;
    #pragma unroll
    for (int r = 0; r < 4; ++r) {
      int px = pxg * 32 + m * 16 + kgrp * 4 + r;
      float giv = sigm_f(vi[r] + bi);
      float gfv = sigm_f(vf[r] + bfg);
      float ggv = tanh_f(vg[r] + bgg);
      float gov = sigm_f(vo[r] + bog);
      int cidx = ((b * HH + y) * WW + px) * 64 + hc;
      float cold = (t > 0) ? cbuf[cidx] : 0.f;
      float cn = gfv * cold + giv * ggv;
      cbuf[cidx] = cn;
      float hn = gov * tanh_f(cn);

      float res;
      int colc = px + DIL;  // center tap column in the staged tile
      int swz = (colc & 7) << 4;
      if constexpr (L == 0) {
        float s = rbv;
        #pragma unroll
        for (int kc = 0; kc < 4; ++kc) {
          int off = ((1 * Wp + colc) * 64 + kc * 16) ^ swz;  // j=0 rows hold x ch 0..31
          bf16x8 xv = *(const bf16x8*)(alds + off);
          #pragma unroll
          for (int e = 0; e < 8; ++e) s += rwv[kc * 8 + e] * (float)xv[e];
        }
        res = s;
      } else {
        int jx = hc >> 5;  // x channels 0..63 live in c-chunks j=0,1
        int off = (((jx * 3 + 1) * Wp + colc) * 64 + (hc & 31) * 2) ^ swz;
        res = (float)*(const bf16*)(alds + off);
      }
      float ho = hn + res;
      hov[r] = ho;
      int hslot = t & (HS - 1);
      hbuf[(size_t)(((hslot * BB + b) * HH + y) * WW + px) * 64 + hc] = (bf16)ho;
    }
    if constexpr (L == 2) {
      int px0 = pxg * 32 + m * 16 + kgrp * 4;
      *(f32x4*)(dout + (size_t)(((b * TT + t) * HID + hc) * HH + y) * WW + px0) = hov;
    }
  }
}

extern "C" void kernel_launch(void* const* d_in, const int* in_sizes, int n_in,
                              void* d_out, int out_size, void* d_ws, size_t ws_size,
                              hipStream_t stream) {
  const float* x_seq = (const float*)d_in[0];
  const float* gw0 = (const float*)d_in[1];
  const float* gb0 = (const float*)d_in[2];
  const float* gw1 = (const float*)d_in[3];
  const float* gb1 = (const float*)d_in[4];
  const float* gw2 = (const float*)d_in[5];
  const float* gb2 = (const float*)d_in[6];
  const float* rw0 = (const float*)d_in[7];
  const float* rb0 = (const float*)d_in[8];
  float* dout = (float*)d_out;

  char* ws = (char*)d_ws;
  size_t off = 0;
  auto carve = [&](size_t bytes) {
    char* p = ws + off;
    off += (bytes + 255) & ~(size_t)255;
    return p;
  };
  bf16* xb0 = (bf16*)carve((size_t)TT * BB * HH * WW * 32 * 2);   // 16.8 MB
  bf16* seqA = (bf16*)carve((size_t)TT * BB * HH * WW * 64 * 2);  // 33.6 MB
  bf16* seqB = (bf16*)carve((size_t)TT * BB * HH * WW * 64 * 2);  // 33.6 MB
  bf16* hC = (bf16*)carve((size_t)2 * BB * HH * WW * 64 * 2);     // 4.2 MB
  float* cbuf = (float*)carve((size_t)BB * HH * WW * 64 * 4);     // 4.2 MB
  bf16* bm0 = (bf16*)carve((size_t)27 * 256 * 32 * 2);
  bf16* bm1 = (bf16*)carve((size_t)36 * 256 * 32 * 2);
  bf16* bm2 = (bf16*)carve((size_t)36 * 256 * 32 * 2);
  bf16* rwb = (bf16*)carve((size_t)64 * 32 * 2);

  {
    int total = TT * BB * HH * WW * 32;
    xpose_kernel<<<(total + 255) / 256, 256, 0, stream>>>(x_seq, xb0);
  }
  {
    int total = 256 * 96 * 9 + 64 * 32;
    wprep_kernel<96><<<(total + 255) / 256, 256, 0, stream>>>(gw0, bm0, rw0, rwb);
  }
  {
    int total = 256 * 128 * 9;
    wprep_kernel<128><<<(total + 255) / 256, 256, 0, stream>>>(gw1, bm1, nullptr, nullptr);
    wprep_kernel<128><<<(total + 255) / 256, 256, 0, stream>>>(gw2, bm2, nullptr, nullptr);
  }

  for (int t = 0; t < TT; ++t)
    step_kernel<0><<<BB * HH, 512, 0, stream>>>(xb0, seqA, bm0, gb0, cbuf, rwb, rb0, nullptr, t);
  for (int t = 0; t < TT; ++t)
    step_kernel<1><<<BB * HH, 512, 0, stream>>>(seqA, seqB, bm1, gb1, cbuf, nullptr, nullptr, nullptr, t);
  for (int t = 0; t < TT; ++t)
    step_kernel<2><<<BB * HH, 512, 0, stream>>>(seqB, hC, bm2, gb2, cbuf, nullptr, nullptr, dout, t);
}